// Round 14
// baseline (3539.138 us; speedup 1.0000x reference)
//
#include <hip/hip_runtime.h>
#include <hip/hip_bf16.h>
#include <math.h>

#define LB __launch_bounds__(256)

namespace {
constexpr int BB  = 64;     // batch
constexpr int LAT = 512;    // latent
constexpr int FE  = 256;    // n_features
constexpr int TT  = 512;    // seq_len
constexpr int G4  = 2048;   // 4*latent
constexpr int LO1 = 1024;   // 2T
constexpr int LO2 = 2048;   // 4T
constexpr int Y1S = 1025;   // Y1 row stride per batch (l=0..1023 + zero pad row)
constexpr float EPSV = 1e-5f;

// workspace offsets (floats)
constexpr size_t OFF_WT   = 0;                                // W_comb^T [2048][512] f32
constexpr size_t OFF_WTB  = OFF_WT  + (size_t)G4 * LAT;       // W_comb^T bf16 [2048][512]
constexpr size_t OFF_BC   = OFF_WTB + (size_t)G4 * LAT / 2;   // b_comb [2048]
constexpr size_t OFF_HX0  = OFF_BC  + G4;                     // tagged pairs buf0 [512][64] u32
constexpr size_t OFF_HX1  = OFF_HX0 + (size_t)LAT * BB;
constexpr size_t OFF_A    = OFF_HX1 + (size_t)LAT * BB;       // A [3][512][256] f32
constexpr size_t OFF_CBV  = OFF_A   + (size_t)3 * LAT * FE;   // cbv [3][256]
constexpr size_t OFF_GSUM = OFF_CBV + 3 * FE;
constexpr size_t OFF_GSQ  = OFF_GSUM + FE;
constexpr size_t OFF_BNSC = OFF_GSQ  + FE;
constexpr size_t OFF_BNSH = OFF_BNSC + FE;
constexpr size_t OFF_BSH  = OFF_BNSH + FE;                    // bias_sh [3][256]
constexpr size_t OFF_BP1  = OFF_BSH + 3 * FE;                 // Bpack1: 3*16*16*64*8 bf16
constexpr size_t OFF_BP2  = OFF_BP1 + (size_t)3*16*16*64*8/2; // Bpack2: 3*8*16*64*8 bf16
constexpr size_t OFF_HSB  = OFF_BP2 + (size_t)3*8*16*64*8/2;  // Hs bf16 [513*64][512]
constexpr size_t OFF_Y1P  = OFF_HSB + (size_t)513*64*512/2;   // Y1 bf16 [64][1025][256]
} // namespace

typedef __attribute__((ext_vector_type(8))) short s8v;
typedef __attribute__((ext_vector_type(4))) float f4v;
typedef __attribute__((ext_vector_type(4))) unsigned u4v;

// ---- device-coherent (sc0 sc1) helpers ----
__device__ __forceinline__ void store_wt_u(unsigned* p, unsigned v) {
    asm volatile("global_store_dword %0, %1, off sc0 sc1" :: "v"(p), "v"(v) : "memory");
}
// pack h (RN bf16 hi16) + epoch tag (lo16) in ONE dword: atomic data+validity
__device__ __forceinline__ unsigned pack_pair(float h, int ep) {
    return ((__float_as_uint(h) + 0x8000u) & 0xFFFF0000u) | (unsigned)ep;
}
__device__ __forceinline__ unsigned short f2bf(float h) {
    return (unsigned short)((__float_as_uint(h) + 0x8000u) >> 16);
}
__device__ __forceinline__ float sigmoid_fast(float x) {
    return 1.f / (1.f + __expf(-x));
}
__device__ __forceinline__ float tanh_fast(float x) {   // cancellation-free
    float e = __expf(2.f * fminf(x, 15.f));
    return (e - 1.f) / (e + 1.f);
}

// W_comb^T[g][k] = W_hh[g][k] + sum_c W_dense[c][k] * W_ih[g][c]; emit f32 + bf16
__global__ LB void k_build_wcomb(const float* __restrict__ Wd, const float* __restrict__ Wih,
                                 const float* __restrict__ Whh, float* __restrict__ Wt,
                                 unsigned short* __restrict__ Wtb) {
    int idx = blockIdx.x * 256 + threadIdx.x;
    int k = idx & (LAT - 1);
    int g = idx >> 9;
    float acc = Whh[(size_t)g * LAT + k];
#pragma unroll 4
    for (int c = 0; c < FE; ++c)
        acc = fmaf(Wd[(size_t)c * LAT + k], Wih[(size_t)g * FE + c], acc);
    Wt[(size_t)g * LAT + k] = acc;
    Wtb[(size_t)g * LAT + k] = f2bf(acc);
}

// b_comb[g] = b_ih[g] + b_hh[g] + sum_c W_ih[g][c]*b_dense[c]
__global__ LB void k_build_bcomb(const float* __restrict__ Wih, const float* __restrict__ bih,
                                 const float* __restrict__ bhh, const float* __restrict__ bd,
                                 float* __restrict__ bc) {
    int g = blockIdx.x * 256 + threadIdx.x;
    float acc = bih[g] + bhh[g];
#pragma unroll 4
    for (int c = 0; c < FE; ++c) acc = fmaf(Wih[(size_t)g * FE + c], bd[c], acc);
    bc[g] = acc;
}

// A[tap][k][co] = sum_c Wd[c][k] * w1[c][co][tap]   (dense fused into deconv1)
__global__ LB void k_build_A(const float* __restrict__ Wd, const float* __restrict__ w1,
                             float* __restrict__ A) {
    int idx = blockIdx.x * 256 + threadIdx.x;      // 3*512*256
    int co = idx & 255, ki = (idx >> 8) & 511, tap = idx >> 17;
    float acc = 0.f;
#pragma unroll 4
    for (int c = 0; c < FE; ++c)
        acc = fmaf(Wd[(size_t)c * LAT + ki], w1[((size_t)c * FE + co) * 3 + tap], acc);
    A[((size_t)tap * LAT + ki) * FE + co] = acc;
}

// cbv[tap][co] = sum_c bd[c] * w1[c][co][tap]
__global__ LB void k_build_cb(const float* __restrict__ bd, const float* __restrict__ w1,
                              float* __restrict__ cbv) {
    int tap = blockIdx.x, co = threadIdx.x;
    float acc = 0.f;
#pragma unroll 4
    for (int c = 0; c < FE; ++c) acc = fmaf(bd[c], w1[((size_t)c * FE + co) * 3 + tap], acc);
    cbv[tap * FE + co] = acc;
}

// Bpack1: fragment-major bf16 layout of A for 16x16x32 MFMA B-operand.
__global__ LB void k_bpack1(const float* __restrict__ A, unsigned short* __restrict__ Bp1) {
    int idx = blockIdx.x * 256 + threadIdx.x;      // 393216
    int j = idx & 7, lane = (idx >> 3) & 63, ct = (idx >> 9) & 15;
    int ks = (idx >> 13) & 15, tap = idx >> 17;
    int k = ks * 32 + (lane >> 4) * 8 + j;
    int co = ct * 16 + (lane & 15);
    Bp1[idx] = f2bf(A[((size_t)tap * LAT + k) * FE + co]);
}

// zero tag buffers + BN accumulators (replay determinism)
__global__ LB void k_init_misc(float* __restrict__ gsum, float* __restrict__ gsq,
                               unsigned* __restrict__ Hx0, unsigned* __restrict__ Hx1) {
    int idx = blockIdx.x * 256 + threadIdx.x;      // 32768
    Hx0[idx] = 0u;
    Hx1[idx] = 0u;
    if (idx < FE) { gsum[idx] = 0.f; gsq[idx] = 0.f; }
}

// zero pad rows: Hs_bf t=512 (64x512) and Y1p row 1024 per batch (64x256)
__global__ LB void k_init_pads(unsigned short* __restrict__ Hsb,
                               unsigned short* __restrict__ Y1p) {
    int idx = blockIdx.x * 256 + threadIdx.x;      // 49152
    if (idx < 32768) {
        Hsb[(size_t)512 * BB * LAT + idx] = 0;
    } else {
        int j = idx - 32768;
        int b = j >> 8, co = j & 255;
        Y1p[((size_t)b * Y1S + 1024) * FE + co] = 0;
    }
}

// 8 sc1 tagged loads, offsets 0..1792 (jj stride 256B), outputs u[o..o+7]
#define LDQ8(o, p)                                                              \
    asm volatile(                                                               \
        "global_load_dword %0, %8, off sc0 sc1\n\t"                             \
        "global_load_dword %1, %8, off offset:256 sc0 sc1\n\t"                  \
        "global_load_dword %2, %8, off offset:512 sc0 sc1\n\t"                  \
        "global_load_dword %3, %8, off offset:768 sc0 sc1\n\t"                  \
        "global_load_dword %4, %8, off offset:1024 sc0 sc1\n\t"                 \
        "global_load_dword %5, %8, off offset:1280 sc0 sc1\n\t"                 \
        "global_load_dword %6, %8, off offset:1536 sc0 sc1\n\t"                 \
        "global_load_dword %7, %8, off offset:1792 sc0 sc1"                     \
        : "=&v"(u[(o)+0]), "=&v"(u[(o)+1]), "=&v"(u[(o)+2]), "=&v"(u[(o)+3]),   \
          "=&v"(u[(o)+4]), "=&v"(u[(o)+5]), "=&v"(u[(o)+6]), "=&v"(u[(o)+7])    \
        : "v"(p))

// Persistent MFMA LSTM scan. 128 WGs x 256 thr (4 waves).
// WG w: M-tile m=w>>5 (batches 16m..16m+15), j-tile jt=w&31 (j 16jt..16jt+15).
// Wave s computes gate-type s's 16x16 tile via 16x mfma_16x16x32_bf16 (K=512).
// B-frags (W_comb bf16) persistent in 64 VGPRs/wave. h exchange = R7 tagged
// dataflow (monolithic optimistic load, wave-__all validate, retry, trailing
// barrier delay). i/f/g/o exchanged via 4KB LDS; 256 threads = 16b x 16j update.
__global__ __launch_bounds__(256, 1) void k_lstm_mfma(
    const unsigned short* __restrict__ Wtb, const float* __restrict__ bc,
    const float* __restrict__ h0, const float* __restrict__ c0,
    unsigned* __restrict__ Hx0, unsigned* __restrict__ Hx1,
    unsigned short* __restrict__ Hsb)
{
    __shared__ float gbuf[4][16][16];    // [s][batch_local][j_local]
    const int w = blockIdx.x, tid = threadIdx.x;
    const int s = tid >> 6, lane = tid & 63;
    const int m = w >> 5, jt = w & 31;

    // persistent B-frags: wave s, lane l covers gate col g = s*512+jt*16+(l&15)
    s8v Bf[16];
    {
        int g = s * LAT + jt * 16 + (lane & 15);
        const unsigned short* bp = Wtb + (size_t)g * LAT + (lane >> 4) * 8;
#pragma unroll
        for (int ks = 0; ks < 16; ++ks)
            Bf[ks] = *(const s8v*)(bp + ks * 32);
    }

    // update role: thread tid <-> (b_loc=tid>>4, j_loc=tid&15)
    const int j_loc = tid & 15, b_loc = tid >> 4;
    const int jg = jt * 16 + j_loc, bg = m * 16 + b_loc;
    float creg = c0[(size_t)bg * LAT + jg];
    const float bs0 = bc[0 * LAT + jg], bs1 = bc[1 * LAT + jg];
    const float bs2 = bc[2 * LAT + jg], bs3 = bc[3 * LAT + jg];
    store_wt_u(&Hx0[jg * BB + bg], pack_pair(h0[(size_t)bg * LAT + jg], 1));

    for (int t = 0; t < TT; ++t) {
        const unsigned* __restrict__ cur = (t & 1) ? Hx1 : Hx0;
        unsigned* __restrict__ nxt = (t & 1) ? Hx0 : Hx1;
        const int ep = t + 1;

        // A-operand: lane l row = batch 16m+(l&15); k = ks*32+(l>>4)*8+jj.
        // dword index = k*64 + b; base = (l>>4)*512 + 16m + (l&15); ks += 2048.
        unsigned u[128];
        const unsigned* pb = cur + (lane >> 4) * 512 + m * 16 + (lane & 15);
        for (;;) {
            LDQ8(0,   pb);
            LDQ8(8,   pb + 2048);
            LDQ8(16,  pb + 4096);
            LDQ8(24,  pb + 6144);
            LDQ8(32,  pb + 8192);
            LDQ8(40,  pb + 10240);
            LDQ8(48,  pb + 12288);
            LDQ8(56,  pb + 14336);
            LDQ8(64,  pb + 16384);
            LDQ8(72,  pb + 18432);
            LDQ8(80,  pb + 20480);
            LDQ8(88,  pb + 22528);
            LDQ8(96,  pb + 24576);
            LDQ8(104, pb + 26624);
            LDQ8(112, pb + 28672);
            LDQ8(120, pb + 30720);
            asm volatile("s_waitcnt vmcnt(0)" ::: "memory");
            __builtin_amdgcn_sched_barrier(0);
            int mn = 0x7fffffff;
#pragma unroll
            for (int i = 0; i < 128; ++i) mn = min(mn, (int)(u[i] & 0xFFFFu));
            if (__all(mn >= ep)) break;      // wave-uniform retry (MFMA is collective)
            __builtin_amdgcn_s_sleep(2);
        }

        // pack bf16 A-frags from tagged dwords (hi16 = payload) + 16 MFMA
        f4v acc = (f4v){0.f, 0.f, 0.f, 0.f};
#pragma unroll
        for (int ks = 0; ks < 16; ++ks) {
            unsigned w0 = (u[ks*8+0] >> 16) | (u[ks*8+1] & 0xFFFF0000u);
            unsigned w1 = (u[ks*8+2] >> 16) | (u[ks*8+3] & 0xFFFF0000u);
            unsigned w2 = (u[ks*8+4] >> 16) | (u[ks*8+5] & 0xFFFF0000u);
            unsigned w3 = (u[ks*8+6] >> 16) | (u[ks*8+7] & 0xFFFF0000u);
            u4v aw = (u4v){w0, w1, w2, w3};
            acc = __builtin_amdgcn_mfma_f32_16x16x32_bf16(
                      __builtin_bit_cast(s8v, aw), Bf[ks], acc, 0, 0, 0);
        }
        // C/D: col = lane&15 (j), row = (lane>>4)*4+q (batch_local)
#pragma unroll
        for (int q = 0; q < 4; ++q)
            gbuf[s][(lane >> 4) * 4 + q][lane & 15] = acc[q];
        __syncthreads();

        {   // all 256 threads: one (b,j) cell each
            float gi = gbuf[0][b_loc][j_loc] + bs0;
            float gf = gbuf[1][b_loc][j_loc] + bs1;
            float gg = gbuf[2][b_loc][j_loc] + bs2;
            float go = gbuf[3][b_loc][j_loc] + bs3;
            float ii = sigmoid_fast(gi);
            float ff = sigmoid_fast(gf);
            float tg = tanh_fast(gg);
            float oo = sigmoid_fast(go);
            creg = ff * creg + ii * tg;
            float hv = oo * tanh_fast(creg);
            unsigned pk = pack_pair(hv, t + 2);
            store_wt_u(&nxt[jg * BB + bg], pk);                   // publish h^{t+1}
            Hsb[((size_t)t * BB + bg) * LAT + jg] = (unsigned short)(pk >> 16);
        }
        __syncthreads();                 // gbuf protect + R13 delay->tag-hit lesson
    }
}

// MFMA deconv1: even/odd outputs as 3 GEMMs (taps 1,2,0; tap0 uses rows+64,
// boundary handled by zero pad rows + bias correction). relu + BN stats + bf16 Y1.
__global__ LB void k_mfma_dc1(const unsigned short* __restrict__ Hsb,
                              const unsigned short* __restrict__ Bp1,
                              const float* __restrict__ cbv, const float* __restrict__ b1,
                              unsigned short* __restrict__ Y1p,
                              float* __restrict__ gsum, float* __restrict__ gsq) {
    __shared__ float s_sum[64], s_sq[64];
    int blk = blockIdx.x;                // 2048: bm(512) x bn(4)
    int bm = blk >> 2, bn = blk & 3;
    int tid = threadIdx.x, wv = tid >> 6, lane = tid & 63;
    if (tid < 64) { s_sum[tid] = 0.f; s_sq[tid] = 0.f; }
    __syncthreads();
    int m0 = bm * 64 + wv * 16;
    const unsigned short* pa = Hsb + (size_t)(m0 + (lane & 15)) * LAT + (lane >> 4) * 8;
    const unsigned short* pas = pa + (size_t)64 * LAT;   // rows r+64 (i+1)
    f4v acce[4], acco[4];
#pragma unroll
    for (int c = 0; c < 4; ++c) { acce[c] = (f4v){0.f,0.f,0.f,0.f}; acco[c] = (f4v){0.f,0.f,0.f,0.f}; }
    for (int ks = 0; ks < 16; ++ks) {
        s8v av = *(const s8v*)(pa + ks * 32);
        s8v as = *(const s8v*)(pas + ks * 32);
#pragma unroll
        for (int c = 0; c < 4; ++c) {
            int ct = bn * 4 + c;
            const size_t fb = ((size_t)ks * 16 + ct) * 64 + lane;
            s8v bf1 = *(const s8v*)(Bp1 + (((size_t)1 * 16 * 16 * 64) + fb) * 8);
            s8v bf2 = *(const s8v*)(Bp1 + (((size_t)2 * 16 * 16 * 64) + fb) * 8);
            s8v bf0 = *(const s8v*)(Bp1 + (fb) * 8);
            acce[c] = __builtin_amdgcn_mfma_f32_16x16x32_bf16(av, bf1, acce[c], 0, 0, 0);
            acco[c] = __builtin_amdgcn_mfma_f32_16x16x32_bf16(av, bf2, acco[c], 0, 0, 0);
            acco[c] = __builtin_amdgcn_mfma_f32_16x16x32_bf16(as, bf0, acco[c], 0, 0, 0);
        }
    }
#pragma unroll
    for (int c = 0; c < 4; ++c) {
        int col = bn * 64 + c * 16 + (lane & 15);
        float be = cbv[FE + col] + b1[col];
        float bo = cbv[2 * FE + col] + b1[col] + cbv[col];
        float c0v = cbv[col];
        float ps = 0.f, pq = 0.f;
#pragma unroll
        for (int q = 0; q < 4; ++q) {
            int r = m0 + (lane >> 4) * 4 + q;      // C/D: row=(lane>>4)*4+q, col=lane&15
            int i = r >> 6, b = r & 63;
            float ve = acce[c][q] + be;
            float vo = acco[c][q] + bo;
            if (i == TT - 1) vo -= c0v;            // tap0 invalid at i+1==512
            ve = fmaxf(ve, 0.f);
            vo = fmaxf(vo, 0.f);
            size_t base = ((size_t)b * Y1S + 2 * i) * FE + col;
            Y1p[base] = f2bf(ve);
            Y1p[base + FE] = f2bf(vo);
            ps += ve + vo;
            pq += ve * ve + vo * vo;
        }
        atomicAdd(&s_sum[c * 16 + (lane & 15)], ps);
        atomicAdd(&s_sq[c * 16 + (lane & 15)], pq);
    }
    __syncthreads();
    if (tid < 64) {
        atomicAdd(&gsum[bn * 64 + tid], s_sum[tid]);
        atomicAdd(&gsq[bn * 64 + tid], s_sq[tid]);
    }
}

__global__ LB void k_bnfin(const float* __restrict__ gsum, const float* __restrict__ gsq,
                           const float* __restrict__ gamma, const float* __restrict__ beta,
                           float* __restrict__ bnsc, float* __restrict__ bnsh) {
    int co = threadIdx.x;
    float n = (float)(BB * LO1);
    float m = gsum[co] / n;
    float v = gsq[co] / n - m * m;
    float sc = gamma[co] / sqrtf(v + EPSV);
    bnsc[co] = sc;
    bnsh[co] = beta[co] - m * sc;
}

// bias_sh[tap][co] = sum_ci bnsh[ci] * w2[ci][co][tap]
__global__ LB void k_fold_bias2(const float* __restrict__ bnsh, const float* __restrict__ w2,
                                float* __restrict__ bsh) {
    int tap = blockIdx.x, co = threadIdx.x;
    float acc = 0.f;
#pragma unroll 4
    for (int c = 0; c < FE; ++c) acc = fmaf(bnsh[c], w2[((size_t)c * FE + co) * 3 + tap], acc);
    bsh[tap * FE + co] = acc;
}

// Bpack2: fragment-major bf16 of (bnsc-folded) w2: [tap][ks(8)][ct(16)][lane][8]
__global__ LB void k_bpack2(const float* __restrict__ bnsc, const float* __restrict__ w2,
                            unsigned short* __restrict__ Bp2) {
    int idx = blockIdx.x * 256 + threadIdx.x;      // 196608
    int j = idx & 7, lane = (idx >> 3) & 63, ct = (idx >> 9) & 15;
    int ks = (idx >> 13) & 7, tap = idx >> 16;
    int ci = ks * 32 + (lane >> 4) * 8 + j;
    int co = ct * 16 + (lane & 15);
    Bp2[idx] = f2bf(bnsc[ci] * w2[((size_t)ci * FE + co) * 3 + tap]);
}

// MFMA deconv2: BN folded into weights; reads bf16 Y1 (pad row 1024 = 0),
// writes fp32 output [B][4T][F].
__global__ LB void k_mfma_dc2(const unsigned short* __restrict__ Y1p,
                              const unsigned short* __restrict__ Bp2,
                              const float* __restrict__ b2, const float* __restrict__ bsh,
                              float* __restrict__ out) {
    int blk = blockIdx.x;                // 4096: b(64) x lt(16) x bn(4)
    int b = blk >> 6, lt = (blk >> 2) & 15, bn = blk & 3;
    int tid = threadIdx.x, wv = tid >> 6, lane = tid & 63;
    int l0 = lt * 64 + wv * 16;
    const unsigned short* pa = Y1p + ((size_t)b * Y1S + l0 + (lane & 15)) * FE + (lane >> 4) * 8;
    const unsigned short* pas = pa + FE;           // rows l+1 (pad at 1024)
    f4v acce[4], acco[4];
#pragma unroll
    for (int c = 0; c < 4; ++c) { acce[c] = (f4v){0.f,0.f,0.f,0.f}; acco[c] = (f4v){0.f,0.f,0.f,0.f}; }
    for (int ks = 0; ks < 8; ++ks) {
        s8v av = *(const s8v*)(pa + ks * 32);
        s8v as = *(const s8v*)(pas + ks * 32);
#pragma unroll
        for (int c = 0; c < 4; ++c) {
            int ct = bn * 4 + c;
            const size_t fb = ((size_t)ks * 16 + ct) * 64 + lane;
            s8v bf1 = *(const s8v*)(Bp2 + (((size_t)1 * 8 * 16 * 64) + fb) * 8);
            s8v bf2 = *(const s8v*)(Bp2 + (((size_t)2 * 8 * 16 * 64) + fb) * 8);
            s8v bf0 = *(const s8v*)(Bp2 + (fb) * 8);
            acce[c] = __builtin_amdgcn_mfma_f32_16x16x32_bf16(av, bf1, acce[c], 0, 0, 0);
            acco[c] = __builtin_amdgcn_mfma_f32_16x16x32_bf16(av, bf2, acco[c], 0, 0, 0);
            acco[c] = __builtin_amdgcn_mfma_f32_16x16x32_bf16(as, bf0, acco[c], 0, 0, 0);
        }
    }
#pragma unroll
    for (int c = 0; c < 4; ++c) {
        int col = bn * 64 + c * 16 + (lane & 15);
        float be = b2[col] + bsh[FE + col];
        float bo = b2[col] + bsh[2 * FE + col] + bsh[col];
        float s0 = bsh[col];
#pragma unroll
        for (int q = 0; q < 4; ++q) {
            int l = l0 + (lane >> 4) * 4 + q;
            float ve = acce[c][q] + be;
            float vo = acco[c][q] + bo;
            if (l == LO1 - 1) vo -= s0;            // tap0 invalid at l+1==1024
            size_t base = ((size_t)b * LO2 + 2 * l) * FE + col;
            out[base] = ve;
            out[base + FE] = vo;
        }
    }
}

extern "C" void kernel_launch(void* const* d_in, const int* in_sizes, int n_in,
                              void* d_out, int out_size, void* d_ws, size_t ws_size,
                              hipStream_t stream) {
    const float* h0    = (const float*)d_in[0];
    const float* c0    = (const float*)d_in[1];
    // d_in[2] = seq_len (int, statically 512)
    const float* Wih   = (const float*)d_in[3];
    const float* bih   = (const float*)d_in[4];
    const float* Whh   = (const float*)d_in[5];
    const float* bhh   = (const float*)d_in[6];
    const float* Wd    = (const float*)d_in[7];
    const float* bd    = (const float*)d_in[8];
    const float* w1    = (const float*)d_in[9];
    const float* b1    = (const float*)d_in[10];
    const float* w2    = (const float*)d_in[11];
    const float* b2    = (const float*)d_in[12];
    const float* gamma = (const float*)d_in[13];
    const float* beta  = (const float*)d_in[14];

    float* ws   = (float*)d_ws;
    float* Wt   = ws + OFF_WT;
    unsigned short* Wtb = (unsigned short*)(ws + OFF_WTB);
    float* bc   = ws + OFF_BC;
    unsigned* Hx0 = (unsigned*)(ws + OFF_HX0);
    unsigned* Hx1 = (unsigned*)(ws + OFF_HX1);
    float* A    = ws + OFF_A;
    float* cbv  = ws + OFF_CBV;
    float* gsum = ws + OFF_GSUM;
    float* gsq  = ws + OFF_GSQ;
    float* bnsc = ws + OFF_BNSC;
    float* bnsh = ws + OFF_BNSH;
    float* bsh  = ws + OFF_BSH;
    unsigned short* Bp1 = (unsigned short*)(ws + OFF_BP1);
    unsigned short* Bp2 = (unsigned short*)(ws + OFF_BP2);
    unsigned short* Hsb = (unsigned short*)(ws + OFF_HSB);
    unsigned short* Y1p = (unsigned short*)(ws + OFF_Y1P);
    float* out  = (float*)d_out;

    k_build_wcomb<<<4096, 256, 0, stream>>>(Wd, Wih, Whh, Wt, Wtb);
    k_build_bcomb<<<8, 256, 0, stream>>>(Wih, bih, bhh, bd, bc);
    k_build_A<<<1536, 256, 0, stream>>>(Wd, w1, A);
    k_build_cb<<<3, 256, 0, stream>>>(bd, w1, cbv);
    k_bpack1<<<1536, 256, 0, stream>>>(A, Bp1);
    k_init_misc<<<128, 256, 0, stream>>>(gsum, gsq, Hx0, Hx1);
    k_init_pads<<<192, 256, 0, stream>>>(Hsb, Y1p);

    {
        const unsigned short* a0 = Wtb;  const float* a1 = bc;
        const float* a2 = h0;  const float* a3 = c0;
        unsigned* a4 = Hx0; unsigned* a5 = Hx1; unsigned short* a6 = Hsb;
        void* args[] = { (void*)&a0, (void*)&a1, (void*)&a2, (void*)&a3,
                         (void*)&a4, (void*)&a5, (void*)&a6 };
        hipLaunchCooperativeKernel((const void*)k_lstm_mfma, dim3(128), dim3(256),
                                   args, 0, stream);
    }

    k_mfma_dc1<<<2048, 256, 0, stream>>>(Hsb, Bp1, cbv, b1, Y1p, gsum, gsq);
    k_bnfin<<<1, 256, 0, stream>>>(gsum, gsq, gamma, beta, bnsc, bnsh);
    k_fold_bias2<<<3, 256, 0, stream>>>(bnsh, w2, bsh);
    k_bpack2<<<768, 256, 0, stream>>>(bnsc, w2, Bp2);
    k_mfma_dc2<<<4096, 256, 0, stream>>>(Y1p, Bp2, b2, bsh, out);
}

// Round 15
// 2754.482 us; speedup vs baseline: 1.2849x; 1.2849x over previous
//
#include <hip/hip_runtime.h>
#include <hip/hip_bf16.h>
#include <math.h>

#define LB __launch_bounds__(256)

namespace {
constexpr int BB  = 64;     // batch
constexpr int LAT = 512;    // latent
constexpr int FE  = 256;    // n_features
constexpr int TT  = 512;    // seq_len
constexpr int G4  = 2048;   // 4*latent
constexpr int LO1 = 1024;   // 2T
constexpr int LO2 = 2048;   // 4T
constexpr int Y1S = 1025;   // Y1 row stride per batch (l=0..1023 + zero pad row)
constexpr float EPSV = 1e-5f;
constexpr int SMEM_BYTES = 134144;   // w_lds 64K + s_red 65K + gfin 2K

// workspace offsets (floats)
constexpr size_t OFF_WT   = 0;                                // W_comb^T [2048][512] f32
constexpr size_t OFF_BC   = OFF_WT  + (size_t)G4 * LAT;       // b_comb [2048]
constexpr size_t OFF_HX   = OFF_BC  + G4;                     // tagged group bufs [4][2][512*16] u32
constexpr size_t OFF_A    = OFF_HX  + (size_t)4 * 2 * 8192;   // A [3][512][256] f32
constexpr size_t OFF_CBV  = OFF_A   + (size_t)3 * LAT * FE;   // cbv [3][256]
constexpr size_t OFF_GSUM = OFF_CBV + 3 * FE;
constexpr size_t OFF_GSQ  = OFF_GSUM + FE;
constexpr size_t OFF_BNSC = OFF_GSQ  + FE;
constexpr size_t OFF_BNSH = OFF_BNSC + FE;
constexpr size_t OFF_BSH  = OFF_BNSH + FE;                    // bias_sh [3][256]
constexpr size_t OFF_BP1  = OFF_BSH + 3 * FE;                 // Bpack1: 3*16*16*64*8 bf16
constexpr size_t OFF_BP2  = OFF_BP1 + (size_t)3*16*16*64*8/2; // Bpack2: 3*8*16*64*8 bf16
constexpr size_t OFF_HSB  = OFF_BP2 + (size_t)3*8*16*64*8/2;  // Hs bf16 [513*64][512]
constexpr size_t OFF_Y1P  = OFF_HSB + (size_t)513*64*512/2;   // Y1 bf16 [64][1025][256]
} // namespace

typedef __attribute__((ext_vector_type(8))) short s8v;
typedef __attribute__((ext_vector_type(4))) float f4v;

// ---- device-coherent (sc0 sc1) helpers ----
__device__ __forceinline__ void store_wt_u(unsigned* p, unsigned v) {
    asm volatile("global_store_dword %0, %1, off sc0 sc1" :: "v"(p), "v"(v) : "memory");
}
// pack h (RN bf16 hi16) + epoch tag (lo16) in ONE dword: atomic data+validity
__device__ __forceinline__ unsigned pack_pair(float h, int ep) {
    return ((__float_as_uint(h) + 0x8000u) & 0xFFFF0000u) | (unsigned)ep;
}
__device__ __forceinline__ unsigned short f2bf(float h) {
    return (unsigned short)((__float_as_uint(h) + 0x8000u) >> 16);
}
__device__ __forceinline__ float sigmoid_fast(float x) {
    return 1.f / (1.f + __expf(-x));
}
__device__ __forceinline__ float tanh_fast(float x) {   // cancellation-free
    float e = __expf(2.f * fminf(x, 15.f));
    return (e - 1.f) / (e + 1.f);
}

// W_comb^T[g][k] = W_hh[g][k] + sum_c W_dense[c][k] * W_ih[g][c]
__global__ LB void k_build_wcomb(const float* __restrict__ Wd, const float* __restrict__ Wih,
                                 const float* __restrict__ Whh, float* __restrict__ Wt) {
    int idx = blockIdx.x * 256 + threadIdx.x;
    int k = idx & (LAT - 1);
    int g = idx >> 9;
    float acc = Whh[(size_t)g * LAT + k];
#pragma unroll 4
    for (int c = 0; c < FE; ++c)
        acc = fmaf(Wd[(size_t)c * LAT + k], Wih[(size_t)g * FE + c], acc);
    Wt[(size_t)g * LAT + k] = acc;
}

// b_comb[g] = b_ih[g] + b_hh[g] + sum_c W_ih[g][c]*b_dense[c]
__global__ LB void k_build_bcomb(const float* __restrict__ Wih, const float* __restrict__ bih,
                                 const float* __restrict__ bhh, const float* __restrict__ bd,
                                 float* __restrict__ bc) {
    int g = blockIdx.x * 256 + threadIdx.x;
    float acc = bih[g] + bhh[g];
#pragma unroll 4
    for (int c = 0; c < FE; ++c) acc = fmaf(Wih[(size_t)g * FE + c], bd[c], acc);
    bc[g] = acc;
}

// A[tap][k][co] = sum_c Wd[c][k] * w1[c][co][tap]   (dense fused into deconv1)
__global__ LB void k_build_A(const float* __restrict__ Wd, const float* __restrict__ w1,
                             float* __restrict__ A) {
    int idx = blockIdx.x * 256 + threadIdx.x;      // 3*512*256
    int co = idx & 255, ki = (idx >> 8) & 511, tap = idx >> 17;
    float acc = 0.f;
#pragma unroll 4
    for (int c = 0; c < FE; ++c)
        acc = fmaf(Wd[(size_t)c * LAT + ki], w1[((size_t)c * FE + co) * 3 + tap], acc);
    A[((size_t)tap * LAT + ki) * FE + co] = acc;
}

// cbv[tap][co] = sum_c bd[c] * w1[c][co][tap]
__global__ LB void k_build_cb(const float* __restrict__ bd, const float* __restrict__ w1,
                              float* __restrict__ cbv) {
    int tap = blockIdx.x, co = threadIdx.x;
    float acc = 0.f;
#pragma unroll 4
    for (int c = 0; c < FE; ++c) acc = fmaf(bd[c], w1[((size_t)c * FE + co) * 3 + tap], acc);
    cbv[tap * FE + co] = acc;
}

// Bpack1: fragment-major bf16 layout of A for 16x16x32 MFMA B-operand.
__global__ LB void k_bpack1(const float* __restrict__ A, unsigned short* __restrict__ Bp1) {
    int idx = blockIdx.x * 256 + threadIdx.x;      // 393216
    int j = idx & 7, lane = (idx >> 3) & 63, ct = (idx >> 9) & 15;
    int ks = (idx >> 13) & 15, tap = idx >> 17;
    int k = ks * 32 + (lane >> 4) * 8 + j;
    int co = ct * 16 + (lane & 15);
    Bp1[idx] = f2bf(A[((size_t)tap * LAT + k) * FE + co]);
}

// zero tagged group buffers + BN accumulators (replay determinism)
__global__ LB void k_init_misc(float* __restrict__ gsum, float* __restrict__ gsq,
                               unsigned* __restrict__ Hx) {
    int idx = blockIdx.x * 256 + threadIdx.x;      // 65536
    Hx[idx] = 0u;
    if (idx < FE) { gsum[idx] = 0.f; gsq[idx] = 0.f; }
}

// zero pad rows: Hs_bf t=512 (64x512) and Y1p row 1024 per batch (64x256)
__global__ LB void k_init_pads(unsigned short* __restrict__ Hsb,
                               unsigned short* __restrict__ Y1p) {
    int idx = blockIdx.x * 256 + threadIdx.x;      // 49152
    if (idx < 32768) {
        Hsb[(size_t)512 * BB * LAT + idx] = 0;
    } else {
        int j = idx - 32768;
        int b = j >> 8, co = j & 255;
        Y1p[((size_t)b * Y1S + 1024) * FE + co] = 0;
    }
}

// 16 sc1 tagged loads from base p, 64B stride (group-local h rows of 16 dwords)
#define LDW16(p)                                                                \
    asm volatile(                                                               \
        "global_load_dword %0,  %16, off sc0 sc1\n\t"                           \
        "global_load_dword %1,  %16, off offset:64 sc0 sc1\n\t"                 \
        "global_load_dword %2,  %16, off offset:128 sc0 sc1\n\t"                \
        "global_load_dword %3,  %16, off offset:192 sc0 sc1\n\t"                \
        "global_load_dword %4,  %16, off offset:256 sc0 sc1\n\t"                \
        "global_load_dword %5,  %16, off offset:320 sc0 sc1\n\t"                \
        "global_load_dword %6,  %16, off offset:384 sc0 sc1\n\t"                \
        "global_load_dword %7,  %16, off offset:448 sc0 sc1\n\t"                \
        "global_load_dword %8,  %16, off offset:512 sc0 sc1\n\t"                \
        "global_load_dword %9,  %16, off offset:576 sc0 sc1\n\t"                \
        "global_load_dword %10, %16, off offset:640 sc0 sc1\n\t"                \
        "global_load_dword %11, %16, off offset:704 sc0 sc1\n\t"                \
        "global_load_dword %12, %16, off offset:768 sc0 sc1\n\t"                \
        "global_load_dword %13, %16, off offset:832 sc0 sc1\n\t"                \
        "global_load_dword %14, %16, off offset:896 sc0 sc1\n\t"                \
        "global_load_dword %15, %16, off offset:960 sc0 sc1"                    \
        : "=&v"(u[0]), "=&v"(u[1]), "=&v"(u[2]), "=&v"(u[3]),                   \
          "=&v"(u[4]), "=&v"(u[5]), "=&v"(u[6]), "=&v"(u[7]),                   \
          "=&v"(u[8]), "=&v"(u[9]), "=&v"(u[10]), "=&v"(u[11]),                 \
          "=&v"(u[12]), "=&v"(u[13]), "=&v"(u[14]), "=&v"(u[15])                \
        : "v"(p))

// Persistent group-scan LSTM. 256 WGs x 512 thr; 4 independent batch groups.
// WG (g = w>>6, jt = w&63): group g (batches 16g..16g+15), j-cols [8jt,8jt+8).
// W slice 32 gate rows x 512 in LDS (fp32, 64KB). h exchange: R7 tagged-dword
// protocol on per-group [512 j][16 b] double buffers -> 32 KB load/WG/step
// (4x less chip traffic than R13), sync domain = 64 WGs. Thread (b=tid&15,
// kq=tid>>4): loads k-slice [16kq,16kq+16), computes all 32 gate cols.
__global__ __launch_bounds__(512, 1) void k_lstm_grp(
    const float* __restrict__ Wt, const float* __restrict__ bc,
    const float* __restrict__ h0, const float* __restrict__ c0,
    unsigned* __restrict__ Hx, unsigned short* __restrict__ Hsb)
{
    extern __shared__ float smem[];
    float* w_lds = smem;                  // [32][512]        64 KB
    float* s_red = smem + 16384;          // [32][520] padded 65 KB (bank-free)
    float* gfin  = smem + 16384 + 16640;  // [32][16]          2 KB
    const int w = blockIdx.x, tid = threadIdx.x;
    const int g = w >> 6, jt = w & 63;
    const int b = tid & 15, kq = tid >> 4;
    unsigned* buf0 = Hx + (size_t)g * 2 * 8192;
    unsigned* buf1 = buf0 + 8192;

    // stage W slice: 32 rows (c = s*8+p -> gate col s*512 + 8jt + p)
    for (int i = tid; i < 4096; i += 512) {
        int c = i >> 7, k4 = i & 127;
        int gg = (c >> 3) * LAT + jt * 8 + (c & 7);
        ((float4*)&w_lds[c * 512])[k4] = ((const float4*)&Wt[(size_t)gg * LAT])[k4];
    }

    // update role: tid<128 <-> (p = tid>>4, b3 = tid&15); owns (j=8jt+p, bg)
    float creg = 0.f, bs0 = 0.f, bs1 = 0.f, bs2 = 0.f, bs3 = 0.f;
    if (tid < 128) {
        int p = tid >> 4, b3 = tid & 15;
        int j = jt * 8 + p, bg = g * 16 + b3;
        creg = c0[(size_t)bg * LAT + j];
        bs0 = bc[0 * LAT + j];
        bs1 = bc[1 * LAT + j];
        bs2 = bc[2 * LAT + j];
        bs3 = bc[3 * LAT + j];
        store_wt_u(&buf0[j * 16 + b3], pack_pair(h0[(size_t)bg * LAT + j], 1));
    }
    __syncthreads();

    for (int t = 0; t < TT; ++t) {
        const unsigned* __restrict__ cur = (t & 1) ? buf1 : buf0;
        unsigned* __restrict__ nxt = (t & 1) ? buf0 : buf1;
        const int ep = t + 1;

        // monolithic optimistic load + wave validate (R7-proven protocol)
        unsigned u[16];
        const unsigned* pb = cur + kq * 256 + b;
        for (;;) {
            LDW16(pb);
            asm volatile("s_waitcnt vmcnt(0)" ::: "memory");
            __builtin_amdgcn_sched_barrier(0);
            int mn = 0x7fffffff;
#pragma unroll
            for (int i = 0; i < 16; ++i) mn = min(mn, (int)(u[i] & 0xFFFFu));
            if (__all(mn >= ep)) break;
            __builtin_amdgcn_s_sleep(2);
        }

        // FMA: 32 gate cols over 16-k slice (tag bits < bf16 ulp of payload)
        float acc[32];
#pragma unroll
        for (int c = 0; c < 32; ++c) acc[c] = 0.f;
#pragma unroll
        for (int i4 = 0; i4 < 4; ++i4) {
            int k = kq * 16 + i4 * 4;
            float h0v = __uint_as_float(u[i4 * 4 + 0]);
            float h1v = __uint_as_float(u[i4 * 4 + 1]);
            float h2v = __uint_as_float(u[i4 * 4 + 2]);
            float h3v = __uint_as_float(u[i4 * 4 + 3]);
#pragma unroll
            for (int c = 0; c < 32; ++c) {
                float4 wv = *(const float4*)&w_lds[c * 512 + k];
                acc[c] = fmaf(h3v, wv.w, fmaf(h2v, wv.z,
                         fmaf(h1v, wv.y, fmaf(h0v, wv.x, acc[c]))));
            }
        }
#pragma unroll
        for (int c = 0; c < 32; ++c) s_red[kq * 520 + c * 16 + b] = acc[c];
        __syncthreads();

        {   // tree stage: thread (c2, b2) sums 32 kq partials
            int c2 = tid >> 4, b2 = tid & 15;
            float sum = 0.f;
#pragma unroll
            for (int q = 0; q < 32; ++q) sum += s_red[q * 520 + c2 * 16 + b2];
            gfin[c2 * 16 + b2] = sum;
        }
        __syncthreads();

        if (tid < 128) {                 // gates, state update, publish
            int p = tid >> 4, b3 = tid & 15;
            int j = jt * 8 + p, bg = g * 16 + b3;
            float gi = gfin[p * 16 + b3] + bs0;
            float gf = gfin[(8 + p) * 16 + b3] + bs1;
            float gg2 = gfin[(16 + p) * 16 + b3] + bs2;
            float go = gfin[(24 + p) * 16 + b3] + bs3;
            float ii = sigmoid_fast(gi);
            float ff = sigmoid_fast(gf);
            float tg = tanh_fast(gg2);
            float oo = sigmoid_fast(go);
            creg = ff * creg + ii * tg;
            float hv = oo * tanh_fast(creg);
            unsigned pk = pack_pair(hv, t + 2);
            store_wt_u(&nxt[j * 16 + b3], pk);                    // publish h^{t+1}
            Hsb[((size_t)t * BB + bg) * LAT + j] = (unsigned short)(pk >> 16);
        }
        __syncthreads();                 // gfin/s_red protect + issue-delay (R13)
    }
}

// MFMA deconv1: even/odd outputs as 3 GEMMs (taps 1,2,0; tap0 uses rows+64,
// boundary handled by zero pad rows + bias correction). relu + BN stats + bf16 Y1.
__global__ LB void k_mfma_dc1(const unsigned short* __restrict__ Hsb,
                              const unsigned short* __restrict__ Bp1,
                              const float* __restrict__ cbv, const float* __restrict__ b1,
                              unsigned short* __restrict__ Y1p,
                              float* __restrict__ gsum, float* __restrict__ gsq) {
    __shared__ float s_sum[64], s_sq[64];
    int blk = blockIdx.x;                // 2048: bm(512) x bn(4)
    int bm = blk >> 2, bn = blk & 3;
    int tid = threadIdx.x, wv = tid >> 6, lane = tid & 63;
    if (tid < 64) { s_sum[tid] = 0.f; s_sq[tid] = 0.f; }
    __syncthreads();
    int m0 = bm * 64 + wv * 16;
    const unsigned short* pa = Hsb + (size_t)(m0 + (lane & 15)) * LAT + (lane >> 4) * 8;
    const unsigned short* pas = pa + (size_t)64 * LAT;   // rows r+64 (i+1)
    f4v acce[4], acco[4];
#pragma unroll
    for (int c = 0; c < 4; ++c) { acce[c] = (f4v){0.f,0.f,0.f,0.f}; acco[c] = (f4v){0.f,0.f,0.f,0.f}; }
    for (int ks = 0; ks < 16; ++ks) {
        s8v av = *(const s8v*)(pa + ks * 32);
        s8v as = *(const s8v*)(pas + ks * 32);
#pragma unroll
        for (int c = 0; c < 4; ++c) {
            int ct = bn * 4 + c;
            const size_t fb = ((size_t)ks * 16 + ct) * 64 + lane;
            s8v bf1 = *(const s8v*)(Bp1 + (((size_t)1 * 16 * 16 * 64) + fb) * 8);
            s8v bf2 = *(const s8v*)(Bp1 + (((size_t)2 * 16 * 16 * 64) + fb) * 8);
            s8v bf0 = *(const s8v*)(Bp1 + (fb) * 8);
            acce[c] = __builtin_amdgcn_mfma_f32_16x16x32_bf16(av, bf1, acce[c], 0, 0, 0);
            acco[c] = __builtin_amdgcn_mfma_f32_16x16x32_bf16(av, bf2, acco[c], 0, 0, 0);
            acco[c] = __builtin_amdgcn_mfma_f32_16x16x32_bf16(as, bf0, acco[c], 0, 0, 0);
        }
    }
#pragma unroll
    for (int c = 0; c < 4; ++c) {
        int col = bn * 64 + c * 16 + (lane & 15);
        float be = cbv[FE + col] + b1[col];
        float bo = cbv[2 * FE + col] + b1[col] + cbv[col];
        float c0v = cbv[col];
        float ps = 0.f, pq = 0.f;
#pragma unroll
        for (int q = 0; q < 4; ++q) {
            int r = m0 + (lane >> 4) * 4 + q;      // C/D: row=(lane>>4)*4+q, col=lane&15
            int i = r >> 6, b = r & 63;
            float ve = acce[c][q] + be;
            float vo = acco[c][q] + bo;
            if (i == TT - 1) vo -= c0v;            // tap0 invalid at i+1==512
            ve = fmaxf(ve, 0.f);
            vo = fmaxf(vo, 0.f);
            size_t base = ((size_t)b * Y1S + 2 * i) * FE + col;
            Y1p[base] = f2bf(ve);
            Y1p[base + FE] = f2bf(vo);
            ps += ve + vo;
            pq += ve * ve + vo * vo;
        }
        atomicAdd(&s_sum[c * 16 + (lane & 15)], ps);
        atomicAdd(&s_sq[c * 16 + (lane & 15)], pq);
    }
    __syncthreads();
    if (tid < 64) {
        atomicAdd(&gsum[bn * 64 + tid], s_sum[tid]);
        atomicAdd(&gsq[bn * 64 + tid], s_sq[tid]);
    }
}

__global__ LB void k_bnfin(const float* __restrict__ gsum, const float* __restrict__ gsq,
                           const float* __restrict__ gamma, const float* __restrict__ beta,
                           float* __restrict__ bnsc, float* __restrict__ bnsh) {
    int co = threadIdx.x;
    float n = (float)(BB * LO1);
    float m = gsum[co] / n;
    float v = gsq[co] / n - m * m;
    float sc = gamma[co] / sqrtf(v + EPSV);
    bnsc[co] = sc;
    bnsh[co] = beta[co] - m * sc;
}

// bias_sh[tap][co] = sum_ci bnsh[ci] * w2[ci][co][tap]
__global__ LB void k_fold_bias2(const float* __restrict__ bnsh, const float* __restrict__ w2,
                                float* __restrict__ bsh) {
    int tap = blockIdx.x, co = threadIdx.x;
    float acc = 0.f;
#pragma unroll 4
    for (int c = 0; c < FE; ++c) acc = fmaf(bnsh[c], w2[((size_t)c * FE + co) * 3 + tap], acc);
    bsh[tap * FE + co] = acc;
}

// Bpack2: fragment-major bf16 of (bnsc-folded) w2: [tap][ks(8)][ct(16)][lane][8]
__global__ LB void k_bpack2(const float* __restrict__ bnsc, const float* __restrict__ w2,
                            unsigned short* __restrict__ Bp2) {
    int idx = blockIdx.x * 256 + threadIdx.x;      // 196608
    int j = idx & 7, lane = (idx >> 3) & 63, ct = (idx >> 9) & 15;
    int ks = (idx >> 13) & 7, tap = idx >> 16;
    int ci = ks * 32 + (lane >> 4) * 8 + j;
    int co = ct * 16 + (lane & 15);
    Bp2[idx] = f2bf(bnsc[ci] * w2[((size_t)ci * FE + co) * 3 + tap]);
}

// MFMA deconv2: BN folded into weights; reads bf16 Y1 (pad row 1024 = 0),
// writes fp32 output [B][4T][F].
__global__ LB void k_mfma_dc2(const unsigned short* __restrict__ Y1p,
                              const unsigned short* __restrict__ Bp2,
                              const float* __restrict__ b2, const float* __restrict__ bsh,
                              float* __restrict__ out) {
    int blk = blockIdx.x;                // 4096: b(64) x lt(16) x bn(4)
    int b = blk >> 6, lt = (blk >> 2) & 15, bn = blk & 3;
    int tid = threadIdx.x, wv = tid >> 6, lane = tid & 63;
    int l0 = lt * 64 + wv * 16;
    const unsigned short* pa = Y1p + ((size_t)b * Y1S + l0 + (lane & 15)) * FE + (lane >> 4) * 8;
    const unsigned short* pas = pa + FE;           // rows l+1 (pad at 1024)
    f4v acce[4], acco[4];
#pragma unroll
    for (int c = 0; c < 4; ++c) { acce[c] = (f4v){0.f,0.f,0.f,0.f}; acco[c] = (f4v){0.f,0.f,0.f,0.f}; }
    for (int ks = 0; ks < 8; ++ks) {
        s8v av = *(const s8v*)(pa + ks * 32);
        s8v as = *(const s8v*)(pas + ks * 32);
#pragma unroll
        for (int c = 0; c < 4; ++c) {
            int ct = bn * 4 + c;
            const size_t fb = ((size_t)ks * 16 + ct) * 64 + lane;
            s8v bf1 = *(const s8v*)(Bp2 + (((size_t)1 * 8 * 16 * 64) + fb) * 8);
            s8v bf2 = *(const s8v*)(Bp2 + (((size_t)2 * 8 * 16 * 64) + fb) * 8);
            s8v bf0 = *(const s8v*)(Bp2 + (fb) * 8);
            acce[c] = __builtin_amdgcn_mfma_f32_16x16x32_bf16(av, bf1, acce[c], 0, 0, 0);
            acco[c] = __builtin_amdgcn_mfma_f32_16x16x32_bf16(av, bf2, acco[c], 0, 0, 0);
            acco[c] = __builtin_amdgcn_mfma_f32_16x16x32_bf16(as, bf0, acco[c], 0, 0, 0);
        }
    }
#pragma unroll
    for (int c = 0; c < 4; ++c) {
        int col = bn * 64 + c * 16 + (lane & 15);
        float be = b2[col] + bsh[FE + col];
        float bo = b2[col] + bsh[2 * FE + col] + bsh[col];
        float s0 = bsh[col];
#pragma unroll
        for (int q = 0; q < 4; ++q) {
            int l = l0 + (lane >> 4) * 4 + q;
            float ve = acce[c][q] + be;
            float vo = acco[c][q] + bo;
            if (l == LO1 - 1) vo -= s0;            // tap0 invalid at l+1==1024
            size_t base = ((size_t)b * LO2 + 2 * l) * FE + col;
            out[base] = ve;
            out[base + FE] = vo;
        }
    }
}

extern "C" void kernel_launch(void* const* d_in, const int* in_sizes, int n_in,
                              void* d_out, int out_size, void* d_ws, size_t ws_size,
                              hipStream_t stream) {
    const float* h0    = (const float*)d_in[0];
    const float* c0    = (const float*)d_in[1];
    // d_in[2] = seq_len (int, statically 512)
    const float* Wih   = (const float*)d_in[3];
    const float* bih   = (const float*)d_in[4];
    const float* Whh   = (const float*)d_in[5];
    const float* bhh   = (const float*)d_in[6];
    const float* Wd    = (const float*)d_in[7];
    const float* bd    = (const float*)d_in[8];
    const float* w1    = (const float*)d_in[9];
    const float* b1    = (const float*)d_in[10];
    const float* w2    = (const float*)d_in[11];
    const float* b2    = (const float*)d_in[12];
    const float* gamma = (const float*)d_in[13];
    const float* beta  = (const float*)d_in[14];

    float* ws   = (float*)d_ws;
    float* Wt   = ws + OFF_WT;
    float* bc   = ws + OFF_BC;
    unsigned* Hx  = (unsigned*)(ws + OFF_HX);
    float* A    = ws + OFF_A;
    float* cbv  = ws + OFF_CBV;
    float* gsum = ws + OFF_GSUM;
    float* gsq  = ws + OFF_GSQ;
    float* bnsc = ws + OFF_BNSC;
    float* bnsh = ws + OFF_BNSH;
    float* bsh  = ws + OFF_BSH;
    unsigned short* Bp1 = (unsigned short*)(ws + OFF_BP1);
    unsigned short* Bp2 = (unsigned short*)(ws + OFF_BP2);
    unsigned short* Hsb = (unsigned short*)(ws + OFF_HSB);
    unsigned short* Y1p = (unsigned short*)(ws + OFF_Y1P);
    float* out  = (float*)d_out;

    static bool attr_set = false;
    if (!attr_set) {
        hipFuncSetAttribute((const void*)k_lstm_grp,
                            hipFuncAttributeMaxDynamicSharedMemorySize, SMEM_BYTES);
        attr_set = true;
    }

    k_build_wcomb<<<4096, 256, 0, stream>>>(Wd, Wih, Whh, Wt);
    k_build_bcomb<<<8, 256, 0, stream>>>(Wih, bih, bhh, bd, bc);
    k_build_A<<<1536, 256, 0, stream>>>(Wd, w1, A);
    k_build_cb<<<3, 256, 0, stream>>>(bd, w1, cbv);
    k_bpack1<<<1536, 256, 0, stream>>>(A, Bp1);
    k_init_misc<<<256, 256, 0, stream>>>(gsum, gsq, Hx);
    k_init_pads<<<192, 256, 0, stream>>>(Hsb, Y1p);

    {
        const float* a0 = Wt;  const float* a1 = bc;
        const float* a2 = h0;  const float* a3 = c0;
        unsigned* a4 = Hx; unsigned short* a5 = Hsb;
        void* args[] = { (void*)&a0, (void*)&a1, (void*)&a2, (void*)&a3,
                         (void*)&a4, (void*)&a5 };
        hipLaunchCooperativeKernel((const void*)k_lstm_grp, dim3(256), dim3(512),
                                   args, SMEM_BYTES, stream);
    }

    k_mfma_dc1<<<2048, 256, 0, stream>>>(Hsb, Bp1, cbv, b1, Y1p, gsum, gsq);
    k_bnfin<<<1, 256, 0, stream>>>(gsum, gsq, gamma, beta, bnsc, bnsh);
    k_fold_bias2<<<3, 256, 0, stream>>>(bnsh, w2, bsh);
    k_bpack2<<<768, 256, 0, stream>>>(bnsc, w2, Bp2);
    k_mfma_dc2<<<4096, 256, 0, stream>>>(Y1p, Bp2, b2, bsh, out);
}

// Round 16
// 1812.055 us; speedup vs baseline: 1.9531x; 1.5201x over previous
//
#include <hip/hip_runtime.h>
#include <hip/hip_bf16.h>
#include <math.h>

#define LB __launch_bounds__(256)

namespace {
constexpr int BB  = 64;     // batch
constexpr int LAT = 512;    // latent
constexpr int FE  = 256;    // n_features
constexpr int TT  = 512;    // seq_len
constexpr int G4  = 2048;   // 4*latent
constexpr int LO1 = 1024;   // 2T
constexpr int LO2 = 2048;   // 4T
constexpr int Y1S = 1025;   // Y1 row stride per batch (l=0..1023 + zero pad row)
constexpr float EPSV = 1e-5f;

// workspace offsets (floats)
constexpr size_t OFF_WT   = 0;                                // W_comb^T [2048][512] f32
constexpr size_t OFF_WTB  = OFF_WT  + (size_t)G4 * LAT;       // W_comb^T bf16
constexpr size_t OFF_BC   = OFF_WTB + (size_t)G4 * LAT / 2;   // b_comb [2048]
constexpr size_t OFF_HX   = OFF_BC  + G4;                     // tagged group bufs [4][2][8192] u32
constexpr size_t OFF_A    = OFF_HX  + (size_t)4 * 2 * 8192;   // A [3][512][256] f32
constexpr size_t OFF_CBV  = OFF_A   + (size_t)3 * LAT * FE;   // cbv [3][256]
constexpr size_t OFF_GSUM = OFF_CBV + 3 * FE;
constexpr size_t OFF_GSQ  = OFF_GSUM + FE;
constexpr size_t OFF_BNSC = OFF_GSQ  + FE;
constexpr size_t OFF_BNSH = OFF_BNSC + FE;
constexpr size_t OFF_BSH  = OFF_BNSH + FE;                    // bias_sh [3][256]
constexpr size_t OFF_BP1  = OFF_BSH + 3 * FE;                 // Bpack1: 3*16*16*64*8 bf16
constexpr size_t OFF_BP2  = OFF_BP1 + (size_t)3*16*16*64*8/2; // Bpack2: 3*8*16*64*8 bf16
constexpr size_t OFF_HSB  = OFF_BP2 + (size_t)3*8*16*64*8/2;  // Hs bf16 [513*64][512]
constexpr size_t OFF_Y1P  = OFF_HSB + (size_t)513*64*512/2;   // Y1 bf16 [64][1025][256]
} // namespace

typedef __attribute__((ext_vector_type(8))) short s8v;
typedef __attribute__((ext_vector_type(4))) float f4v;
typedef __attribute__((ext_vector_type(4))) unsigned u4v;

// ---- device-coherent (sc0 sc1) helpers ----
__device__ __forceinline__ void store_wt_u(unsigned* p, unsigned v) {
    asm volatile("global_store_dword %0, %1, off sc0 sc1" :: "v"(p), "v"(v) : "memory");
}
// pack h (RN bf16 hi16) + epoch tag (lo16) in ONE dword: atomic data+validity
__device__ __forceinline__ unsigned pack_pair(float h, int ep) {
    return ((__float_as_uint(h) + 0x8000u) & 0xFFFF0000u) | (unsigned)ep;
}
__device__ __forceinline__ unsigned short f2bf(float h) {
    return (unsigned short)((__float_as_uint(h) + 0x8000u) >> 16);
}
__device__ __forceinline__ float sigmoid_fast(float x) {
    return 1.f / (1.f + __expf(-x));
}
__device__ __forceinline__ float tanh_fast(float x) {   // cancellation-free
    float e = __expf(2.f * fminf(x, 15.f));
    return (e - 1.f) / (e + 1.f);
}

// W_comb^T[g][k] = W_hh[g][k] + sum_c W_dense[c][k] * W_ih[g][c]; f32 + bf16
__global__ LB void k_build_wcomb(const float* __restrict__ Wd, const float* __restrict__ Wih,
                                 const float* __restrict__ Whh, float* __restrict__ Wt,
                                 unsigned short* __restrict__ Wtb) {
    int idx = blockIdx.x * 256 + threadIdx.x;
    int k = idx & (LAT - 1);
    int g = idx >> 9;
    float acc = Whh[(size_t)g * LAT + k];
#pragma unroll 4
    for (int c = 0; c < FE; ++c)
        acc = fmaf(Wd[(size_t)c * LAT + k], Wih[(size_t)g * FE + c], acc);
    Wt[(size_t)g * LAT + k] = acc;
    Wtb[(size_t)g * LAT + k] = f2bf(acc);
}

// b_comb[g] = b_ih[g] + b_hh[g] + sum_c W_ih[g][c]*b_dense[c]
__global__ LB void k_build_bcomb(const float* __restrict__ Wih, const float* __restrict__ bih,
                                 const float* __restrict__ bhh, const float* __restrict__ bd,
                                 float* __restrict__ bc) {
    int g = blockIdx.x * 256 + threadIdx.x;
    float acc = bih[g] + bhh[g];
#pragma unroll 4
    for (int c = 0; c < FE; ++c) acc = fmaf(Wih[(size_t)g * FE + c], bd[c], acc);
    bc[g] = acc;
}

// A[tap][k][co] = sum_c Wd[c][k] * w1[c][co][tap]   (dense fused into deconv1)
__global__ LB void k_build_A(const float* __restrict__ Wd, const float* __restrict__ w1,
                             float* __restrict__ A) {
    int idx = blockIdx.x * 256 + threadIdx.x;      // 3*512*256
    int co = idx & 255, ki = (idx >> 8) & 511, tap = idx >> 17;
    float acc = 0.f;
#pragma unroll 4
    for (int c = 0; c < FE; ++c)
        acc = fmaf(Wd[(size_t)c * LAT + ki], w1[((size_t)c * FE + co) * 3 + tap], acc);
    A[((size_t)tap * LAT + ki) * FE + co] = acc;
}

// cbv[tap][co] = sum_c bd[c] * w1[c][co][tap]
__global__ LB void k_build_cb(const float* __restrict__ bd, const float* __restrict__ w1,
                              float* __restrict__ cbv) {
    int tap = blockIdx.x, co = threadIdx.x;
    float acc = 0.f;
#pragma unroll 4
    for (int c = 0; c < FE; ++c) acc = fmaf(bd[c], w1[((size_t)c * FE + co) * 3 + tap], acc);
    cbv[tap * FE + co] = acc;
}

// Bpack1: fragment-major bf16 layout of A for 16x16x32 MFMA B-operand.
__global__ LB void k_bpack1(const float* __restrict__ A, unsigned short* __restrict__ Bp1) {
    int idx = blockIdx.x * 256 + threadIdx.x;      // 393216
    int j = idx & 7, lane = (idx >> 3) & 63, ct = (idx >> 9) & 15;
    int ks = (idx >> 13) & 15, tap = idx >> 17;
    int k = ks * 32 + (lane >> 4) * 8 + j;
    int co = ct * 16 + (lane & 15);
    Bp1[idx] = f2bf(A[((size_t)tap * LAT + k) * FE + co]);
}

// zero tagged group buffers + BN accumulators (replay determinism)
__global__ LB void k_init_misc(float* __restrict__ gsum, float* __restrict__ gsq,
                               unsigned* __restrict__ Hx) {
    int idx = blockIdx.x * 256 + threadIdx.x;      // 65536
    Hx[idx] = 0u;
    if (idx < FE) { gsum[idx] = 0.f; gsq[idx] = 0.f; }
}

// zero pad rows: Hs_bf t=512 (64x512) and Y1p row 1024 per batch (64x256)
__global__ LB void k_init_pads(unsigned short* __restrict__ Hsb,
                               unsigned short* __restrict__ Y1p) {
    int idx = blockIdx.x * 256 + threadIdx.x;      // 49152
    if (idx < 32768) {
        Hsb[(size_t)512 * BB * LAT + idx] = 0;
    } else {
        int j = idx - 32768;
        int b = j >> 8, co = j & 255;
        Y1p[((size_t)b * Y1S + 1024) * FE + co] = 0;
    }
}

// 16 sc1 tagged loads from base p, 64B stride, into u[o..o+15]
#define LDG16(o, p)                                                             \
    asm volatile(                                                               \
        "global_load_dword %0,  %16, off sc0 sc1\n\t"                           \
        "global_load_dword %1,  %16, off offset:64 sc0 sc1\n\t"                 \
        "global_load_dword %2,  %16, off offset:128 sc0 sc1\n\t"                \
        "global_load_dword %3,  %16, off offset:192 sc0 sc1\n\t"                \
        "global_load_dword %4,  %16, off offset:256 sc0 sc1\n\t"                \
        "global_load_dword %5,  %16, off offset:320 sc0 sc1\n\t"                \
        "global_load_dword %6,  %16, off offset:384 sc0 sc1\n\t"                \
        "global_load_dword %7,  %16, off offset:448 sc0 sc1\n\t"                \
        "global_load_dword %8,  %16, off offset:512 sc0 sc1\n\t"                \
        "global_load_dword %9,  %16, off offset:576 sc0 sc1\n\t"                \
        "global_load_dword %10, %16, off offset:640 sc0 sc1\n\t"                \
        "global_load_dword %11, %16, off offset:704 sc0 sc1\n\t"                \
        "global_load_dword %12, %16, off offset:768 sc0 sc1\n\t"                \
        "global_load_dword %13, %16, off offset:832 sc0 sc1\n\t"                \
        "global_load_dword %14, %16, off offset:896 sc0 sc1\n\t"                \
        "global_load_dword %15, %16, off offset:960 sc0 sc1"                    \
        : "=&v"(u[(o) + 0]), "=&v"(u[(o) + 1]), "=&v"(u[(o) + 2]),              \
          "=&v"(u[(o) + 3]), "=&v"(u[(o) + 4]), "=&v"(u[(o) + 5]),              \
          "=&v"(u[(o) + 6]), "=&v"(u[(o) + 7]), "=&v"(u[(o) + 8]),              \
          "=&v"(u[(o) + 9]), "=&v"(u[(o) + 10]), "=&v"(u[(o) + 11]),            \
          "=&v"(u[(o) + 12]), "=&v"(u[(o) + 13]), "=&v"(u[(o) + 14]),           \
          "=&v"(u[(o) + 15])                                                    \
        : "v"(p))

// Persistent group-scan LSTM with MFMA compute. 256 WGs x 256 thr (4 waves);
// 4 independent batch groups; WG (g=w>>6, jt=w&63) owns 8 j x 16 b.
// Exchange: R15's proven tagged-dword protocol on [512 j][16 b] group bufs
// (thread b=tid&15, kq=tid>>4 loads j-slice [32kq,32kq+32), validates, retries).
// Compute: payloads staged bf16 into LDS A-tile [16 b][264 dw]; 4 waves
// (n=wv&1 N-tile, kh=wv>>1 K-half) run 8x mfma_16x16x32_bf16 with W as
// persistent bf16 B-frags in VGPRs (R14-verified layout). Partials summed in
// gbuf; threads 0-127 do gates/state/publish.
__global__ __launch_bounds__(256, 1) void k_lstm_grp2(
    const unsigned short* __restrict__ Wtb, const float* __restrict__ bc,
    const float* __restrict__ h0, const float* __restrict__ c0,
    unsigned* __restrict__ Hx, unsigned short* __restrict__ Hsb)
{
    __shared__ unsigned A_lds[16 * 264];     // [b][264] bf16-pair dwords (pad 8)
    __shared__ float gbuf[4][16][16];        // [wave][b][c-in-tile]
    const int w = blockIdx.x, tid = threadIdx.x;
    const int g = w >> 6, jt = w & 63;
    const int b = tid & 15, kq = tid >> 4;
    const int wv = tid >> 6, lane = tid & 63;
    const int n = wv & 1, kh = wv >> 1;
    unsigned* buf0 = Hx + (size_t)g * 2 * 8192;
    unsigned* buf1 = buf0 + 8192;

    // persistent B-frags: wave (n,kh), lane covers gate col c = 16n+(lane&15)
    s8v Bf[8];
    {
        int c = 16 * n + (lane & 15);
        int gg = (c >> 3) * LAT + jt * 8 + (c & 7);
        const unsigned short* bp = Wtb + (size_t)gg * LAT + kh * 256 + (lane >> 4) * 8;
#pragma unroll
        for (int ks = 0; ks < 8; ++ks)
            Bf[ks] = *(const s8v*)(bp + ks * 32);
    }

    // update role: tid<128 <-> (p = tid>>4, b3 = tid&15); owns (j = 8jt+p, bg)
    float creg = 0.f, bs0 = 0.f, bs1 = 0.f, bs2 = 0.f, bs3 = 0.f;
    if (tid < 128) {
        int p = tid >> 4, b3 = tid & 15;
        int j = jt * 8 + p, bg = g * 16 + b3;
        creg = c0[(size_t)bg * LAT + j];
        bs0 = bc[0 * LAT + j];
        bs1 = bc[1 * LAT + j];
        bs2 = bc[2 * LAT + j];
        bs3 = bc[3 * LAT + j];
        store_wt_u(&buf0[j * 16 + b3], pack_pair(h0[(size_t)bg * LAT + j], 1));
    }
    __syncthreads();

    for (int t = 0; t < TT; ++t) {
        const unsigned* __restrict__ cur = (t & 1) ? buf1 : buf0;
        unsigned* __restrict__ nxt = (t & 1) ? buf0 : buf1;
        const int ep = t + 1;

        // ---- monolithic optimistic load + wave validate (R15-proven)
        unsigned u[32];
        const unsigned* pb = cur + kq * 512 + b;
        for (;;) {
            LDG16(0, pb);
            LDG16(16, pb + 256);
            asm volatile("s_waitcnt vmcnt(0)" ::: "memory");
            __builtin_amdgcn_sched_barrier(0);
            int mn = 0x7fffffff;
#pragma unroll
            for (int i = 0; i < 32; ++i) mn = min(mn, (int)(u[i] & 0xFFFFu));
            if (__all(mn >= ep)) break;
            __builtin_amdgcn_s_sleep(2);
        }

        // ---- stage payload bf16 pairs into LDS A-tile [b][kq*16 .. +16)
        {
            unsigned* dst = A_lds + b * 264 + kq * 16;
#pragma unroll
            for (int q4 = 0; q4 < 4; ++q4) {
                u4v v = (u4v){
                    (u[q4*8+0] >> 16) | (u[q4*8+1] & 0xFFFF0000u),
                    (u[q4*8+2] >> 16) | (u[q4*8+3] & 0xFFFF0000u),
                    (u[q4*8+4] >> 16) | (u[q4*8+5] & 0xFFFF0000u),
                    (u[q4*8+6] >> 16) | (u[q4*8+7] & 0xFFFF0000u) };
                *(u4v*)(dst + q4 * 4) = v;
            }
        }
        __syncthreads();

        // ---- 4 waves: 8x MFMA each (A row = batch l&15, k-half kh)
        f4v acc = (f4v){0.f, 0.f, 0.f, 0.f};
#pragma unroll
        for (int ks = 0; ks < 8; ++ks) {
            const unsigned* ap = A_lds + (lane & 15) * 264 + kh * 128 + ks * 16
                               + (lane >> 4) * 4;
            u4v av = *(const u4v*)ap;
            acc = __builtin_amdgcn_mfma_f32_16x16x32_bf16(
                      __builtin_bit_cast(s8v, av), Bf[ks], acc, 0, 0, 0);
        }
#pragma unroll
        for (int q = 0; q < 4; ++q)
            gbuf[wv][(lane >> 4) * 4 + q][lane & 15] = acc[q];   // row=b, col=c
        __syncthreads();

        if (tid < 128) {                 // gates, state update, publish
            int p = tid >> 4, b3 = tid & 15;
            int j = jt * 8 + p, bg = g * 16 + b3;
            // gate col c = s*8+p; tile n=c>>4 sums K-halves gbuf[n]+gbuf[2+n]
            float gi = gbuf[0][b3][p]      + gbuf[2][b3][p];          // c=p
            float gf = gbuf[0][b3][8 + p]  + gbuf[2][b3][8 + p];      // c=8+p
            float gg2 = gbuf[1][b3][p]     + gbuf[3][b3][p];          // c=16+p
            float go = gbuf[1][b3][8 + p]  + gbuf[3][b3][8 + p];      // c=24+p
            gi += bs0; gf += bs1; gg2 += bs2; go += bs3;
            float ii = sigmoid_fast(gi);
            float ff = sigmoid_fast(gf);
            float tg = tanh_fast(gg2);
            float oo = sigmoid_fast(go);
            creg = ff * creg + ii * tg;
            float hv = oo * tanh_fast(creg);
            unsigned pk = pack_pair(hv, t + 2);
            store_wt_u(&nxt[j * 16 + b3], pk);                    // publish h^{t+1}
            Hsb[((size_t)t * BB + bg) * LAT + j] = (unsigned short)(pk >> 16);
        }
        __syncthreads();                 // A_lds/gbuf protect + issue-delay (R13)
    }
}

// MFMA deconv1: even/odd outputs as 3 GEMMs (taps 1,2,0; tap0 uses rows+64,
// boundary handled by zero pad rows + bias correction). relu + BN stats + bf16 Y1.
__global__ LB void k_mfma_dc1(const unsigned short* __restrict__ Hsb,
                              const unsigned short* __restrict__ Bp1,
                              const float* __restrict__ cbv, const float* __restrict__ b1,
                              unsigned short* __restrict__ Y1p,
                              float* __restrict__ gsum, float* __restrict__ gsq) {
    __shared__ float s_sum[64], s_sq[64];
    int blk = blockIdx.x;                // 2048: bm(512) x bn(4)
    int bm = blk >> 2, bn = blk & 3;
    int tid = threadIdx.x, wv = tid >> 6, lane = tid & 63;
    if (tid < 64) { s_sum[tid] = 0.f; s_sq[tid] = 0.f; }
    __syncthreads();
    int m0 = bm * 64 + wv * 16;
    const unsigned short* pa = Hsb + (size_t)(m0 + (lane & 15)) * LAT + (lane >> 4) * 8;
    const unsigned short* pas = pa + (size_t)64 * LAT;   // rows r+64 (i+1)
    f4v acce[4], acco[4];
#pragma unroll
    for (int c = 0; c < 4; ++c) { acce[c] = (f4v){0.f,0.f,0.f,0.f}; acco[c] = (f4v){0.f,0.f,0.f,0.f}; }
    for (int ks = 0; ks < 16; ++ks) {
        s8v av = *(const s8v*)(pa + ks * 32);
        s8v as = *(const s8v*)(pas + ks * 32);
#pragma unroll
        for (int c = 0; c < 4; ++c) {
            int ct = bn * 4 + c;
            const size_t fb = ((size_t)ks * 16 + ct) * 64 + lane;
            s8v bf1 = *(const s8v*)(Bp1 + (((size_t)1 * 16 * 16 * 64) + fb) * 8);
            s8v bf2 = *(const s8v*)(Bp1 + (((size_t)2 * 16 * 16 * 64) + fb) * 8);
            s8v bf0 = *(const s8v*)(Bp1 + (fb) * 8);
            acce[c] = __builtin_amdgcn_mfma_f32_16x16x32_bf16(av, bf1, acce[c], 0, 0, 0);
            acco[c] = __builtin_amdgcn_mfma_f32_16x16x32_bf16(av, bf2, acco[c], 0, 0, 0);
            acco[c] = __builtin_amdgcn_mfma_f32_16x16x32_bf16(as, bf0, acco[c], 0, 0, 0);
        }
    }
#pragma unroll
    for (int c = 0; c < 4; ++c) {
        int col = bn * 64 + c * 16 + (lane & 15);
        float be = cbv[FE + col] + b1[col];
        float bo = cbv[2 * FE + col] + b1[col] + cbv[col];
        float c0v = cbv[col];
        float ps = 0.f, pq = 0.f;
#pragma unroll
        for (int q = 0; q < 4; ++q) {
            int r = m0 + (lane >> 4) * 4 + q;      // C/D: row=(lane>>4)*4+q, col=lane&15
            int i = r >> 6, b = r & 63;
            float ve = acce[c][q] + be;
            float vo = acco[c][q] + bo;
            if (i == TT - 1) vo -= c0v;            // tap0 invalid at i+1==512
            ve = fmaxf(ve, 0.f);
            vo = fmaxf(vo, 0.f);
            size_t base = ((size_t)b * Y1S + 2 * i) * FE + col;
            Y1p[base] = f2bf(ve);
            Y1p[base + FE] = f2bf(vo);
            ps += ve + vo;
            pq += ve * ve + vo * vo;
        }
        atomicAdd(&s_sum[c * 16 + (lane & 15)], ps);
        atomicAdd(&s_sq[c * 16 + (lane & 15)], pq);
    }
    __syncthreads();
    if (tid < 64) {
        atomicAdd(&gsum[bn * 64 + tid], s_sum[tid]);
        atomicAdd(&gsq[bn * 64 + tid], s_sq[tid]);
    }
}

__global__ LB void k_bnfin(const float* __restrict__ gsum, const float* __restrict__ gsq,
                           const float* __restrict__ gamma, const float* __restrict__ beta,
                           float* __restrict__ bnsc, float* __restrict__ bnsh) {
    int co = threadIdx.x;
    float n = (float)(BB * LO1);
    float m = gsum[co] / n;
    float v = gsq[co] / n - m * m;
    float sc = gamma[co] / sqrtf(v + EPSV);
    bnsc[co] = sc;
    bnsh[co] = beta[co] - m * sc;
}

// bias_sh[tap][co] = sum_ci bnsh[ci] * w2[ci][co][tap]
__global__ LB void k_fold_bias2(const float* __restrict__ bnsh, const float* __restrict__ w2,
                                float* __restrict__ bsh) {
    int tap = blockIdx.x, co = threadIdx.x;
    float acc = 0.f;
#pragma unroll 4
    for (int c = 0; c < FE; ++c) acc = fmaf(bnsh[c], w2[((size_t)c * FE + co) * 3 + tap], acc);
    bsh[tap * FE + co] = acc;
}

// Bpack2: fragment-major bf16 of (bnsc-folded) w2: [tap][ks(8)][ct(16)][lane][8]
__global__ LB void k_bpack2(const float* __restrict__ bnsc, const float* __restrict__ w2,
                            unsigned short* __restrict__ Bp2) {
    int idx = blockIdx.x * 256 + threadIdx.x;      // 196608
    int j = idx & 7, lane = (idx >> 3) & 63, ct = (idx >> 9) & 15;
    int ks = (idx >> 13) & 7, tap = idx >> 16;
    int ci = ks * 32 + (lane >> 4) * 8 + j;
    int co = ct * 16 + (lane & 15);
    Bp2[idx] = f2bf(bnsc[ci] * w2[((size_t)ci * FE + co) * 3 + tap]);
}

// MFMA deconv2: BN folded into weights; reads bf16 Y1 (pad row 1024 = 0),
// writes fp32 output [B][4T][F].
__global__ LB void k_mfma_dc2(const unsigned short* __restrict__ Y1p,
                              const unsigned short* __restrict__ Bp2,
                              const float* __restrict__ b2, const float* __restrict__ bsh,
                              float* __restrict__ out) {
    int blk = blockIdx.x;                // 4096: b(64) x lt(16) x bn(4)
    int b = blk >> 6, lt = (blk >> 2) & 15, bn = blk & 3;
    int tid = threadIdx.x, wv = tid >> 6, lane = tid & 63;
    int l0 = lt * 64 + wv * 16;
    const unsigned short* pa = Y1p + ((size_t)b * Y1S + l0 + (lane & 15)) * FE + (lane >> 4) * 8;
    const unsigned short* pas = pa + FE;           // rows l+1 (pad at 1024)
    f4v acce[4], acco[4];
#pragma unroll
    for (int c = 0; c < 4; ++c) { acce[c] = (f4v){0.f,0.f,0.f,0.f}; acco[c] = (f4v){0.f,0.f,0.f,0.f}; }
    for (int ks = 0; ks < 8; ++ks) {
        s8v av = *(const s8v*)(pa + ks * 32);
        s8v as = *(const s8v*)(pas + ks * 32);
#pragma unroll
        for (int c = 0; c < 4; ++c) {
            int ct = bn * 4 + c;
            const size_t fb = ((size_t)ks * 16 + ct) * 64 + lane;
            s8v bf1 = *(const s8v*)(Bp2 + (((size_t)1 * 8 * 16 * 64) + fb) * 8);
            s8v bf2 = *(const s8v*)(Bp2 + (((size_t)2 * 8 * 16 * 64) + fb) * 8);
            s8v bf0 = *(const s8v*)(Bp2 + (fb) * 8);
            acce[c] = __builtin_amdgcn_mfma_f32_16x16x32_bf16(av, bf1, acce[c], 0, 0, 0);
            acco[c] = __builtin_amdgcn_mfma_f32_16x16x32_bf16(av, bf2, acco[c], 0, 0, 0);
            acco[c] = __builtin_amdgcn_mfma_f32_16x16x32_bf16(as, bf0, acco[c], 0, 0, 0);
        }
    }
#pragma unroll
    for (int c = 0; c < 4; ++c) {
        int col = bn * 64 + c * 16 + (lane & 15);
        float be = b2[col] + bsh[FE + col];
        float bo = b2[col] + bsh[2 * FE + col] + bsh[col];
        float s0 = bsh[col];
#pragma unroll
        for (int q = 0; q < 4; ++q) {
            int l = l0 + (lane >> 4) * 4 + q;
            float ve = acce[c][q] + be;
            float vo = acco[c][q] + bo;
            if (l == LO1 - 1) vo -= s0;            // tap0 invalid at l+1==1024
            size_t base = ((size_t)b * LO2 + 2 * l) * FE + col;
            out[base] = ve;
            out[base + FE] = vo;
        }
    }
}

extern "C" void kernel_launch(void* const* d_in, const int* in_sizes, int n_in,
                              void* d_out, int out_size, void* d_ws, size_t ws_size,
                              hipStream_t stream) {
    const float* h0    = (const float*)d_in[0];
    const float* c0    = (const float*)d_in[1];
    // d_in[2] = seq_len (int, statically 512)
    const float* Wih   = (const float*)d_in[3];
    const float* bih   = (const float*)d_in[4];
    const float* Whh   = (const float*)d_in[5];
    const float* bhh   = (const float*)d_in[6];
    const float* Wd    = (const float*)d_in[7];
    const float* bd    = (const float*)d_in[8];
    const float* w1    = (const float*)d_in[9];
    const float* b1    = (const float*)d_in[10];
    const float* w2    = (const float*)d_in[11];
    const float* b2    = (const float*)d_in[12];
    const float* gamma = (const float*)d_in[13];
    const float* beta  = (const float*)d_in[14];

    float* ws   = (float*)d_ws;
    float* Wt   = ws + OFF_WT;
    unsigned short* Wtb = (unsigned short*)(ws + OFF_WTB);
    float* bc   = ws + OFF_BC;
    unsigned* Hx  = (unsigned*)(ws + OFF_HX);
    float* A    = ws + OFF_A;
    float* cbv  = ws + OFF_CBV;
    float* gsum = ws + OFF_GSUM;
    float* gsq  = ws + OFF_GSQ;
    float* bnsc = ws + OFF_BNSC;
    float* bnsh = ws + OFF_BNSH;
    float* bsh  = ws + OFF_BSH;
    unsigned short* Bp1 = (unsigned short*)(ws + OFF_BP1);
    unsigned short* Bp2 = (unsigned short*)(ws + OFF_BP2);
    unsigned short* Hsb = (unsigned short*)(ws + OFF_HSB);
    unsigned short* Y1p = (unsigned short*)(ws + OFF_Y1P);
    float* out  = (float*)d_out;

    k_build_wcomb<<<4096, 256, 0, stream>>>(Wd, Wih, Whh, Wt, Wtb);
    k_build_bcomb<<<8, 256, 0, stream>>>(Wih, bih, bhh, bd, bc);
    k_build_A<<<1536, 256, 0, stream>>>(Wd, w1, A);
    k_build_cb<<<3, 256, 0, stream>>>(bd, w1, cbv);
    k_bpack1<<<1536, 256, 0, stream>>>(A, Bp1);
    k_init_misc<<<256, 256, 0, stream>>>(gsum, gsq, Hx);
    k_init_pads<<<192, 256, 0, stream>>>(Hsb, Y1p);

    {
        const unsigned short* a0 = Wtb;  const float* a1 = bc;
        const float* a2 = h0;  const float* a3 = c0;
        unsigned* a4 = Hx; unsigned short* a5 = Hsb;
        void* args[] = { (void*)&a0, (void*)&a1, (void*)&a2, (void*)&a3,
                         (void*)&a4, (void*)&a5 };
        hipLaunchCooperativeKernel((const void*)k_lstm_grp2, dim3(256), dim3(256),
                                   args, 0, stream);
    }

    k_mfma_dc1<<<2048, 256, 0, stream>>>(Hsb, Bp1, cbv, b1, Y1p, gsum, gsq);
    k_bnfin<<<1, 256, 0, stream>>>(gsum, gsq, gamma, beta, bnsc, bnsh);
    k_fold_bias2<<<3, 256, 0, stream>>>(bnsh, w2, bsh);
    k_bpack2<<<768, 256, 0, stream>>>(bnsc, w2, Bp2);
    k_mfma_dc2<<<4096, 256, 0, stream>>>(Y1p, Bp2, b2, bsh, out);
}